// Round 3
// baseline (12.100 us; speedup 1.0000x reference)
//
#include <hip/hip_runtime.h>

#define NT    2048
#define D     16
#define NSEG  32
#define NOUTC 136

typedef __attribute__((ext_vector_type(8))) short bf16x8;
typedef __attribute__((ext_vector_type(4))) float f32x4;

__global__ __launch_bounds__(128) void logsig_kernel(
    const float* __restrict__ inp,     // [B, NT, D]
    const int*   __restrict__ length,  // [G]
    float*       __restrict__ out,     // [B, NSEG, NOUTC]
    int batch_size)
{
    const int blk  = blockIdx.x;
    const int b    = blk / NSEG;
    const int s    = blk % NSEG;
    const int g    = b / batch_size;
    const int tid  = threadIdx.x;      // 0..127
    const int wave = tid >> 6;         // 0,1 -> k-chunk
    const int lane = tid & 63;

    __shared__ float xT[D * 68];       // [ch][t], stride 68 floats (272B rows, b128-aligned)
    __shared__ float Cs[2][16 * 17];   // per-wave partial C

    // segment boundaries: tv = round(1 + (L-1)*k/32) - 1, bit-match numpy RNE
    const float Lm1 = __fadd_rn((float)length[g], -1.0f);
    const int t0 = (int)rintf(__fadd_rn(1.0f, __fmul_rn(Lm1, (float)s       * (1.0f/32.0f)))) - 1;
    const int t1 = (int)rintf(__fadd_rn(1.0f, __fmul_rn(Lm1, (float)(s + 1) * (1.0f/32.0f)))) - 1;
    const int n  = t1 - t0;            // steps in segment, ~7..64

    const float* xrow = inp + (size_t)b * NT * D;
    const float4* src = (const float4*)(xrow + (size_t)t0 * D);

    // --- stage rows t0..t1 transposed into LDS: 3 independent clamped loads ---
    const int nvec = (n + 1) * 4;      // float4s to stage (<= 260)
    const int v0 = tid, v1 = tid + 128, v2 = tid + 256;
    const float4 q0 = src[min(v0, nvec - 1)];
    const float4 q1 = src[min(v1, nvec - 1)];
    const float4 q2 = src[min(v2, nvec - 1)];

    if (v0 < nvec) {
        const int t = v0 >> 2, c4 = (v0 & 3) << 2;
        xT[(c4 + 0) * 68 + t] = q0.x; xT[(c4 + 1) * 68 + t] = q0.y;
        xT[(c4 + 2) * 68 + t] = q0.z; xT[(c4 + 3) * 68 + t] = q0.w;
    }
    if (v1 < nvec) {
        const int t = v1 >> 2, c4 = (v1 & 3) << 2;
        xT[(c4 + 0) * 68 + t] = q1.x; xT[(c4 + 1) * 68 + t] = q1.y;
        xT[(c4 + 2) * 68 + t] = q1.z; xT[(c4 + 3) * 68 + t] = q1.w;
    }
    if (v2 < nvec) {
        const int t = v2 >> 2, c4 = (v2 & 3) << 2;
        xT[(c4 + 0) * 68 + t] = q2.x; xT[(c4 + 1) * 68 + t] = q2.y;
        xT[(c4 + 2) * 68 + t] = q2.z; xT[(c4 + 3) * 68 + t] = q2.w;
    }
    __syncthreads();

    // --- MFMA: this wave's 32-step k-chunk of M(i,j) = sum_k x_i(k) dx_j(k) ---
    const int ch = lane & 15;
    const int tb = lane >> 4;
    const float* base = &xT[ch * 68];

    f32x4 acc = {0.f, 0.f, 0.f, 0.f};
    if (wave == 0 || n > 32) {         // wave-uniform: skip empty chunk
        const int kb = wave * 32 + 8 * tb;   // first k this lane supplies
        const f32x4 p0 = *(const f32x4*)(base + kb);
        const f32x4 p1 = *(const f32x4*)(base + kb + 4);
        const float x9 = base[kb + 8];
        float xv[9] = {p0[0], p0[1], p0[2], p0[3], p1[0], p1[1], p1[2], p1[3], x9};

        bf16x8 Ah, Al, Bh, Bl;
        #pragma unroll
        for (int e = 0; e < 8; ++e) {
            const int idx = kb + e;
            const float xm  = (idx <= n) ? xv[e] : 0.0f;
            const float dxm = (idx <  n) ? (xv[e + 1] - xv[e]) : 0.0f;
            const unsigned bx = __float_as_uint(xm);
            Ah[e] = (short)(bx >> 16);
            const float lx = xm - __uint_as_float(bx & 0xFFFF0000u);
            Al[e] = (short)(__float_as_uint(lx) >> 16);
            const unsigned bd = __float_as_uint(dxm);
            Bh[e] = (short)(bd >> 16);
            const float ld = dxm - __uint_as_float(bd & 0xFFFF0000u);
            Bl[e] = (short)(__float_as_uint(ld) >> 16);
        }
        acc = __builtin_amdgcn_mfma_f32_16x16x32_bf16(Ah, Bh, acc, 0, 0, 0);
        acc = __builtin_amdgcn_mfma_f32_16x16x32_bf16(Ah, Bl, acc, 0, 0, 0);
        acc = __builtin_amdgcn_mfma_f32_16x16x32_bf16(Al, Bh, acc, 0, 0, 0);
    }

    // acc[e] = partial M(i = 4*tb + e, j = ch); park in LDS
    #pragma unroll
    for (int e = 0; e < 4; ++e)
        Cs[wave][(4 * tb + e) * 17 + ch] = acc[e];
    __syncthreads();

    // --- epilogue ---
    const size_t obase = ((size_t)b * NSEG + s) * NOUTC;
    if (tid < D) {
        out[obase + tid] = xT[tid * 68 + n] - xT[tid * 68];     // lvl1
    }
    if (tid < 120) {
        int p = tid, i = 0;
        while (i < D - 2 && p >= (D - 1 - i)) { p -= (D - 1 - i); ++i; }
        const int j = i + 1 + p;                                 // pair (i<j), tid == triu index
        const float Mij = Cs[0][i * 17 + j] + Cs[1][i * 17 + j];
        const float Mji = Cs[0][j * 17 + i] + Cs[1][j * 17 + i];
        const float xai = xT[i * 68],     xei = xT[i * 68 + n];
        const float xaj = xT[j * 68],     xej = xT[j * 68 + n];
        const float corr = xai * (xej - xaj) - xaj * (xei - xai);
        out[obase + D + tid] = 0.5f * (Mij - Mji - corr);        // lvl2
    }
}

extern "C" void kernel_launch(void* const* d_in, const int* in_sizes, int n_in,
                              void* d_out, int out_size, void* d_ws, size_t ws_size,
                              hipStream_t stream)
{
    const float* inp    = (const float*)d_in[0];
    const int*   length = (const int*)d_in[1];
    float*       out    = (float*)d_out;

    const int B  = in_sizes[0] / (NT * D);   // 128
    const int G  = in_sizes[1];              // 8
    const int bs = B / G;                    // 16

    const int grid = B * NSEG;               // 4096 blocks x 2 waves
    logsig_kernel<<<grid, 128, 0, stream>>>(inp, length, out, bs);
}

// Round 4
// 9.869 us; speedup vs baseline: 1.2260x; 1.2260x over previous
//
#include <hip/hip_runtime.h>

#define NT    2048
#define D     16
#define NSEG  32
#define NOUTC 136

typedef __attribute__((ext_vector_type(8))) short bf16x8;
typedef __attribute__((ext_vector_type(4))) float f32x4;

// pair p -> (i<<4)|j for triu(i<j) row-major order
__device__ const unsigned char PAIR_TAB[120] = {
    0x01,0x02,0x03,0x04,0x05,0x06,0x07,0x08,0x09,0x0A,0x0B,0x0C,0x0D,0x0E,0x0F,
    0x12,0x13,0x14,0x15,0x16,0x17,0x18,0x19,0x1A,0x1B,0x1C,0x1D,0x1E,0x1F,
    0x23,0x24,0x25,0x26,0x27,0x28,0x29,0x2A,0x2B,0x2C,0x2D,0x2E,0x2F,
    0x34,0x35,0x36,0x37,0x38,0x39,0x3A,0x3B,0x3C,0x3D,0x3E,0x3F,
    0x45,0x46,0x47,0x48,0x49,0x4A,0x4B,0x4C,0x4D,0x4E,0x4F,
    0x56,0x57,0x58,0x59,0x5A,0x5B,0x5C,0x5D,0x5E,0x5F,
    0x67,0x68,0x69,0x6A,0x6B,0x6C,0x6D,0x6E,0x6F,
    0x78,0x79,0x7A,0x7B,0x7C,0x7D,0x7E,0x7F,
    0x89,0x8A,0x8B,0x8C,0x8D,0x8E,0x8F,
    0x9A,0x9B,0x9C,0x9D,0x9E,0x9F,
    0xAB,0xAC,0xAD,0xAE,0xAF,
    0xBC,0xBD,0xBE,0xBF,
    0xCD,0xCE,0xCF,
    0xDE,0xDF,
    0xEF
};

__global__ __launch_bounds__(256) void logsig_kernel(
    const float* __restrict__ inp,     // [B, NT, D]
    const int*   __restrict__ length,  // [G]
    float*       __restrict__ out,     // [B, NSEG, NOUTC]
    int batch_size)
{
    const int blk  = blockIdx.x;       // 0..1023
    const int b    = blk >> 3;
    const int sq   = blk & 7;
    const int tid  = threadIdx.x;
    const int wave = tid >> 6;         // 4 independent waves, one segment each
    const int lane = tid & 63;
    const int s    = sq * 4 + wave;
    const int g    = b / batch_size;

    // per-wave LDS slab: Cs[16*17] + xa[16] + xe[16]
    __shared__ float slab[4][16 * 17 + 32];
    float* Cs   = slab[wave];
    float* xa_s = Cs + 272;
    float* xe_s = Cs + 288;

    // segment boundaries: tv = round(1 + (L-1)*k/32) - 1, bit-match numpy RNE
    const float Lm1 = __fadd_rn((float)length[g], -1.0f);
    const int t0 = (int)rintf(__fadd_rn(1.0f, __fmul_rn(Lm1, (float)s       * (1.0f/32.0f)))) - 1;
    const int t1 = (int)rintf(__fadd_rn(1.0f, __fmul_rn(Lm1, (float)(s + 1) * (1.0f/32.0f)))) - 1;
    const int n  = t1 - t0;            // steps, ~7..64

    const float* xrow = inp + (size_t)b * (NT * D);

    const int ch = lane & 15;          // channel this lane supplies
    const int tb = lane >> 4;          // k-block within chunk

    // endpoints (coalesced 64B loads, lanes 0..15)
    if (lane < D) {
        xa_s[lane] = xrow[t0 * D + lane];
        xe_s[lane] = xrow[t1 * D + lane];
    }

    // --- M(i,j) = sum_k x_i(k) dx_j(k) via bf16 hi/lo split, direct global gather ---
    f32x4 acc = {0.f, 0.f, 0.f, 0.f};
    const int nch = (n > 32) ? 2 : 1;  // wave-uniform
    for (int c = 0; c < nch; ++c) {
        const int kb = c * 32 + 8 * tb;
        float xv[9];
        #pragma unroll
        for (int e = 0; e < 9; ++e) {
            int t = t0 + kb + e;                 // clamp: masked lanes must not fault
            t = (t < NT - 1) ? t : (NT - 1);
            xv[e] = xrow[t * D + ch];            // wave-coalesced: 4 x 64B rows per e
        }
        bf16x8 Ah, Al, Bh, Bl;
        #pragma unroll
        for (int e = 0; e < 8; ++e) {
            const int idx = kb + e;
            const float xm  = (idx <= n) ? xv[e] : 0.0f;
            const float dxm = (idx <  n) ? (xv[e + 1] - xv[e]) : 0.0f;
            const unsigned bx = __float_as_uint(xm);
            Ah[e] = (short)(bx >> 16);                               // bf16 hi (truncate)
            const float lx = xm - __uint_as_float(bx & 0xFFFF0000u); // exact remainder
            Al[e] = (short)(__float_as_uint(lx) >> 16);
            const unsigned bd = __float_as_uint(dxm);
            Bh[e] = (short)(bd >> 16);
            const float ld = dxm - __uint_as_float(bd & 0xFFFF0000u);
            Bl[e] = (short)(__float_as_uint(ld) >> 16);
        }
        acc = __builtin_amdgcn_mfma_f32_16x16x32_bf16(Ah, Bh, acc, 0, 0, 0);
        acc = __builtin_amdgcn_mfma_f32_16x16x32_bf16(Ah, Bl, acc, 0, 0, 0);
        acc = __builtin_amdgcn_mfma_f32_16x16x32_bf16(Al, Bh, acc, 0, 0, 0);
    }

    // park C for transpose access: acc[e] = M(i = 4*tb + e, j = ch)
    #pragma unroll
    for (int e = 0; e < 4; ++e)
        Cs[(4 * tb + e) * 17 + ch] = acc[e];
    __syncthreads();   // waves are independent; skew across waves is <= 1 step of work

    // --- epilogue: each lane writes outputs o = lane, lane+64, (lane+128 < 136) ---
    const size_t obase = ((size_t)b * NSEG + s) * NOUTC;
    for (int o = lane; o < NOUTC; o += 64) {
        float val;
        if (o < D) {
            val = xe_s[o] - xa_s[o];                         // lvl1
        } else {
            const int pc = PAIR_TAB[o - D];
            const int i = pc >> 4, j = pc & 15;
            const float Mij = Cs[i * 17 + j];
            const float Mji = Cs[j * 17 + i];
            const float xai = xa_s[i], xaj = xa_s[j];
            const float xei = xe_s[i], xej = xe_s[j];
            const float corr = xai * (xej - xaj) - xaj * (xei - xai);
            val = 0.5f * (Mij - Mji - corr);                 // lvl2
        }
        out[obase + o] = val;
    }
}

extern "C" void kernel_launch(void* const* d_in, const int* in_sizes, int n_in,
                              void* d_out, int out_size, void* d_ws, size_t ws_size,
                              hipStream_t stream)
{
    const float* inp    = (const float*)d_in[0];
    const int*   length = (const int*)d_in[1];
    float*       out    = (float*)d_out;

    const int B  = in_sizes[0] / (NT * D);   // 128
    const int G  = in_sizes[1];              // 8
    const int bs = B / G;                    // 16

    const int grid = B * (NSEG / 4);         // 1024 blocks x 4 waves (one segment each)
    logsig_kernel<<<grid, 256, 0, stream>>>(inp, length, out, bs);
}